// Round 7
// baseline (260.691 us; speedup 1.0000x reference)
//
#include <hip/hip_runtime.h>
#include <math.h>

#define BB 64
#define PP 100
#define NN 1000
#define DD 128
#define HH 8
#define QDQ 16
#define NTOT 1196
#define HALFK 598
#define CH 128
#define QROWS 16
#define LOG2E 1.44269504088896f

// ---------------- Kernel W: transpose Wq and MC (128x128 each) ----------------
__global__ __launch_bounds__(256) void k_wt(const float* __restrict__ Wq,
                                            const float* __restrict__ MC,
                                            float* __restrict__ WqT,
                                            float* __restrict__ MCT) {
  int r = blockIdx.x;            // output row (d)
  int t = threadIdx.x;
  int j = t & 127;
  if (t < 128) WqT[r * DD + j] = Wq[j * DD + r];
  else         MCT[r * DD + j] = MC[j * DD + r];
}

// ---------------- Kernel A: q = q_first + x @ Wq^T (LDS-staged W^T GEMM) ------
__global__ __launch_bounds__(256) void k_qcalc(const float* __restrict__ x,
                                               const float* __restrict__ WqT,
                                               const float* __restrict__ qf,
                                               float* __restrict__ qout) {
  __shared__ float sw[64 * DD];        // 32 KB: one d-half of W^T
  __shared__ float xs[QROWS * DD];     // 8 KB
  int tid = threadIdx.x;
  int row0 = blockIdx.x * QROWS;

  for (int i = tid; i < QROWS * DD / 4; i += 256)
    ((float4*)xs)[i] = ((const float4*)(x + (size_t)row0 * DD))[i];

  int j = tid & 127, rr = tid >> 7;
  float acc[8];
#pragma unroll
  for (int i = 0; i < 8; ++i) acc[i] = 0.f;

  for (int half = 0; half < 2; ++half) {
    __syncthreads();
    for (int i = tid; i < 64 * DD / 4; i += 256)
      ((float4*)sw)[i] = ((const float4*)(WqT + half * 64 * DD))[i];
    __syncthreads();
#pragma unroll
    for (int ri = 0; ri < 8; ++ri) {
      int r = 2 * ri + rr;
      float a = acc[ri];
#pragma unroll 16
      for (int d = 0; d < 64; ++d)
        a += xs[r * DD + half * 64 + d] * sw[d * DD + j];
      acc[ri] = a;
    }
  }
#pragma unroll
  for (int ri = 0; ri < 8; ++ri) {
    int bp = row0 + 2 * ri + rr;
    int b = bp / PP, p = bp % PP;
    int h = j >> 4, qd = j & 15;
    size_t qi = ((size_t)(b * HH + h) * PP + p) * QDQ + qd;
    qout[qi] = acc[ri] + qf[qi];
  }
}

// ---------------- Kernel F: mask transpose+pad, scaled by log2e ---------------
__global__ __launch_bounds__(256) void k_mask_t(const float* __restrict__ mask,
                                                float* __restrict__ mt) {
  __shared__ float tile[64][65];
  int nt = blockIdx.x;           // 19 tiles over n (0..1215, pad to NTOT)
  int pt = blockIdx.y;           // 2 tiles over p (0..127)
  int b  = blockIdx.z;
  int tx = threadIdx.x & 63, ty = threadIdx.x >> 6;
  int n0 = nt * 64, p0 = pt * 64;
#pragma unroll
  for (int r = ty; r < 64; r += 4) {
    int p = p0 + r, n = n0 + tx;
    tile[r][tx] = (p < PP && n < NN) ? mask[((size_t)b * PP + p) * NN + n] * LOG2E : 0.f;
  }
  __syncthreads();
#pragma unroll
  for (int r = ty; r < 64; r += 4) {
    int n = n0 + r, p = p0 + tx;
    if (n < NTOT) mt[((size_t)b * NTOT + n) * 128 + p] = tile[tx][r];
  }
}

// ---------------- Kernel B: MHA partial, 2 queries/lane, wave-per-key-subset --
// grid = 1024 (XCD-swizzled: 512 bh * 2 halves); block = 256 (4 waves)
// wave w computes keys {w, w+4, ...} of each staged 128-key chunk; each lane
// owns query slots lane and lane+64 -> every k/v LDS broadcast feeds 128 FMAs.
__global__ __launch_bounds__(256) void k_mha(const float* __restrict__ kk,
                                             const float* __restrict__ vv,
                                             const float* __restrict__ qws,
                                             const float* __restrict__ mt,
                                             float* __restrict__ part) {
  int bid = blockIdx.x;
  int swz = (bid & 7) * 128 + (bid >> 3);      // 16 blocks of same b per XCD
  int bh = swz >> 1, half = swz & 1;
  int b = bh >> 3;
  int tid = threadIdx.x;
  int w = tid >> 6;           // wave 0..3
  int lane = tid & 63;
  int pc2 = (lane + 64) < PP ? (lane + 64) : PP - 1;   // clamped 2nd query row

  __shared__ __align__(16) float smem_f[9216];  // 36 KB: chunks (32KB) / merge (36KB)
  float4* s4 = (float4*)smem_f;                 // k dbuf: [0..1023], v dbuf: [1024..2047]

  float q1[QDQ], q2[QDQ];
  const float sc0 = 0.25f * LOG2E;              // fold 1/sqrt(16) and log2(e)
  {
    const float* qrow1 = qws + ((size_t)bh * PP + lane) * QDQ;
    const float* qrow2 = qws + ((size_t)bh * PP + pc2) * QDQ;
#pragma unroll
    for (int jj = 0; jj < QDQ; jj += 4) {
      float4 a4 = *(const float4*)(qrow1 + jj);
      q1[jj] = a4.x * sc0; q1[jj + 1] = a4.y * sc0;
      q1[jj + 2] = a4.z * sc0; q1[jj + 3] = a4.w * sc0;
      float4 b4 = *(const float4*)(qrow2 + jj);
      q2[jj] = b4.x * sc0; q2[jj + 1] = b4.y * sc0;
      q2[jj + 2] = b4.z * sc0; q2[jj + 3] = b4.w * sc0;
    }
  }

  float acc1[QDQ], acc2[QDQ];
#pragma unroll
  for (int jj = 0; jj < QDQ; ++jj) { acc1[jj] = 0.f; acc2[jj] = 0.f; }
  float m1 = -1e30f, l1 = 0.f, m2 = -1e30f, l2 = 0.f;   // log2 domain

  const float4* kg4 = (const float4*)(kk + (size_t)bh * NTOT * QDQ);
  const float4* vg4 = (const float4*)(vv + (size_t)bh * NTOT * QDQ);
  int key0 = half * HALFK;
  int gbase = key0 * 4;                        // float4 index of half start
  int lim = NTOT * 4 - 1;

  float4 rk0, rk1, rv0, rv1;
  {
    int g0 = gbase + tid;       g0 = g0 < lim ? g0 : lim;
    int g1 = gbase + tid + 256; g1 = g1 < lim ? g1 : lim;
    rk0 = kg4[g0]; rk1 = kg4[g1]; rv0 = vg4[g0]; rv1 = vg4[g1];
  }

  int cur = 0;
  for (int c = 0; c < 5; ++c) {                // 598 = 4*128 + 86
    int base = c * CH;
    int L = HALFK - base; if (L > CH) L = CH;
    __syncthreads();                           // buf[cur] free (2-chunk-old reads done)
    s4[cur * 512 + tid]         = rk0;
    s4[cur * 512 + 256 + tid]   = rk1;
    s4[1024 + cur * 512 + tid]       = rv0;
    s4[1024 + cur * 512 + 256 + tid] = rv1;
    __syncthreads();
    if (c < 4) {                               // prefetch next chunk into regs
      int g0 = gbase + (c + 1) * 512 + tid;       g0 = g0 < lim ? g0 : lim;
      int g1 = gbase + (c + 1) * 512 + tid + 256; g1 = g1 < lim ? g1 : lim;
      rk0 = kg4[g0]; rk1 = kg4[g1]; rv0 = vg4[g0]; rv1 = vg4[g1];
    }
    const float* mrow = mt + ((size_t)b * NTOT + key0 + base) * 128;
    int kb = cur * 512, vb = 1024 + cur * 512;

    int nk = (L - w + 3) >> 2;                 // this wave's key count (stride 4)
#pragma unroll 2
    for (int j = 0; j < nk; ++j) {
      int i = w + 4 * j;
      float mk1 = mrow[i * 128 + lane];
      float mk2 = mrow[i * 128 + lane + 64];
      float4 k0 = s4[kb + i * 4 + 0], k1 = s4[kb + i * 4 + 1];
      float4 k2 = s4[kb + i * 4 + 2], k3 = s4[kb + i * 4 + 3];
      float s1 = q1[0] * k0.x + q1[1] * k0.y + q1[2] * k0.z + q1[3] * k0.w
               + q1[4] * k1.x + q1[5] * k1.y + q1[6] * k1.z + q1[7] * k1.w
               + q1[8] * k2.x + q1[9] * k2.y + q1[10] * k2.z + q1[11] * k2.w
               + q1[12] * k3.x + q1[13] * k3.y + q1[14] * k3.z + q1[15] * k3.w;
      float s2 = q2[0] * k0.x + q2[1] * k0.y + q2[2] * k0.z + q2[3] * k0.w
               + q2[4] * k1.x + q2[5] * k1.y + q2[6] * k1.z + q2[7] * k1.w
               + q2[8] * k2.x + q2[9] * k2.y + q2[10] * k2.z + q2[11] * k2.w
               + q2[12] * k3.x + q2[13] * k3.y + q2[14] * k3.z + q2[15] * k3.w;
      s1 += mk1; s2 += mk2;
      if (s1 > m1 + 8.f) {                     // deferred-max rescale (rare)
        float cc = exp2f(m1 - s1);
        l1 *= cc;
#pragma unroll
        for (int jj = 0; jj < QDQ; ++jj) acc1[jj] *= cc;
        m1 = s1;
      }
      if (s2 > m2 + 8.f) {
        float cc = exp2f(m2 - s2);
        l2 *= cc;
#pragma unroll
        for (int jj = 0; jj < QDQ; ++jj) acc2[jj] *= cc;
        m2 = s2;
      }
      float w1 = exp2f(s1 - m1), w2 = exp2f(s2 - m2);
      l1 += w1; l2 += w2;
      float4 v0 = s4[vb + i * 4 + 0], v1 = s4[vb + i * 4 + 1];
      float4 v2 = s4[vb + i * 4 + 2], v3 = s4[vb + i * 4 + 3];
      acc1[0] += w1 * v0.x;  acc1[1] += w1 * v0.y;  acc1[2] += w1 * v0.z;  acc1[3] += w1 * v0.w;
      acc1[4] += w1 * v1.x;  acc1[5] += w1 * v1.y;  acc1[6] += w1 * v1.z;  acc1[7] += w1 * v1.w;
      acc1[8] += w1 * v2.x;  acc1[9] += w1 * v2.y;  acc1[10] += w1 * v2.z; acc1[11] += w1 * v2.w;
      acc1[12] += w1 * v3.x; acc1[13] += w1 * v3.y; acc1[14] += w1 * v3.z; acc1[15] += w1 * v3.w;
      acc2[0] += w2 * v0.x;  acc2[1] += w2 * v0.y;  acc2[2] += w2 * v0.z;  acc2[3] += w2 * v0.w;
      acc2[4] += w2 * v1.x;  acc2[5] += w2 * v1.y;  acc2[6] += w2 * v1.z;  acc2[7] += w2 * v1.w;
      acc2[8] += w2 * v2.x;  acc2[9] += w2 * v2.y;  acc2[10] += w2 * v2.z; acc2[11] += w2 * v2.w;
      acc2[12] += w2 * v3.x; acc2[13] += w2 * v3.y; acc2[14] += w2 * v3.z; acc2[15] += w2 * v3.w;
    }
    cur ^= 1;
  }

  __syncthreads();                             // reuse smem for 4-wave merge
  {
    float* pl = smem_f + ((size_t)(w * 128 + lane)) * 18;
#pragma unroll
    for (int jj = 0; jj < QDQ; ++jj) pl[jj] = acc1[jj];
    pl[16] = m1; pl[17] = l1;
    float* ph = smem_f + ((size_t)(w * 128 + lane + 64)) * 18;
#pragma unroll
    for (int jj = 0; jj < QDQ; ++jj) ph[jj] = acc2[jj];
    ph[16] = m2; ph[17] = l2;
  }
  __syncthreads();
  for (int idx = tid; idx < PP * QDQ; idx += 256) {
    int pp2 = idx >> 4, qd = idx & 15;
    float m0 = smem_f[(0 * 128 + pp2) * 18 + 16], l0 = smem_f[(0 * 128 + pp2) * 18 + 17];
    float ma = smem_f[(1 * 128 + pp2) * 18 + 16], la = smem_f[(1 * 128 + pp2) * 18 + 17];
    float mb = smem_f[(2 * 128 + pp2) * 18 + 16], lb = smem_f[(2 * 128 + pp2) * 18 + 17];
    float mc = smem_f[(3 * 128 + pp2) * 18 + 16], lc = smem_f[(3 * 128 + pp2) * 18 + 17];
    float M = fmaxf(fmaxf(m0, ma), fmaxf(mb, mc));
    float c0 = exp2f(m0 - M), c1 = exp2f(ma - M);
    float c2 = exp2f(mb - M), c3 = exp2f(mc - M);
    float A = smem_f[(0 * 128 + pp2) * 18 + qd] * c0 + smem_f[(1 * 128 + pp2) * 18 + qd] * c1
            + smem_f[(2 * 128 + pp2) * 18 + qd] * c2 + smem_f[(3 * 128 + pp2) * 18 + qd] * c3;
    float* o = part + ((size_t)swz * PP + pp2) * 18;
    o[qd] = A;
    if (qd == 0) {
      o[16] = M;                               // log2 domain
      o[17] = l0 * c0 + la * c1 + lb * c2 + lc * c3;
    }
  }
}

// ---------------- Kernel C: merge 2 halves + mh_combine (LDS W^T GEMM) --------
__global__ __launch_bounds__(256) void k_combine(const float* __restrict__ part,
                                                 const float* __restrict__ MCT,
                                                 float* __restrict__ mh) {
  __shared__ float sw[64 * DD];        // 32 KB
  __shared__ float oc[QROWS * DD];     // 8 KB
  int tid = threadIdx.x;
  int row0 = blockIdx.x * QROWS;

  for (int i = tid; i < QROWS * DD; i += 256) {
    int r = i >> 7, t = i & 127;
    int bp = row0 + r, b = bp / PP, p = bp % PP;
    int qd = t & 15, h = t >> 4;
    int bh = b * HH + h;
    const float* r0 = part + ((size_t)(bh * 2 + 0) * PP + p) * 18;
    const float* r1 = part + ((size_t)(bh * 2 + 1) * PP + p) * 18;
    float m0 = r0[16], l0 = r0[17], m1 = r1[16], l1 = r1[17];
    float M = fmaxf(m0, m1);
    float c0 = exp2f(m0 - M), c1 = exp2f(m1 - M);
    float L = l0 * c0 + l1 * c1;
    oc[i] = (r0[qd] * c0 + r1[qd] * c1) / L;
  }

  int j = tid & 127, rr = tid >> 7;
  float acc[8];
#pragma unroll
  for (int i = 0; i < 8; ++i) acc[i] = 0.f;

  for (int half = 0; half < 2; ++half) {
    __syncthreads();
    for (int i = tid; i < 64 * DD / 4; i += 256)
      ((float4*)sw)[i] = ((const float4*)(MCT + half * 64 * DD))[i];
    __syncthreads();
#pragma unroll
    for (int ri = 0; ri < 8; ++ri) {
      int r = 2 * ri + rr;
      float a = acc[ri];
#pragma unroll 16
      for (int d = 0; d < 64; ++d)
        a += oc[r * DD + half * 64 + d] * sw[d * DD + j];
      acc[ri] = a;
    }
  }
#pragma unroll
  for (int ri = 0; ri < 8; ++ri) {
    int bp = row0 + 2 * ri + rr;
    mh[(size_t)bp * DD + j] = acc[ri];
  }
}

// ---------------- Kernel D: score2[b,p,n] = sum_d mh[b,p,d]*shk[b,d,n] --------
__global__ __launch_bounds__(256) void k_score2(const float* __restrict__ mh,
                                                const float* __restrict__ shk,
                                                float* __restrict__ sc) {
  int bid = blockIdx.x;
  int swz = (bid & 7) * 128 + (bid >> 3);      // same-b blocks share an XCD
  int b = swz >> 4, nt = swz & 15;
  int tid = threadIdx.x; int nl = tid & 31, pg = tid >> 5;
  __shared__ float A[PP * 132];
  for (int idx = tid; idx < PP * DD; idx += 256)
    A[(idx >> 7) * 132 + (idx & 127)] = mh[(size_t)b * PP * DD + idx];
  __syncthreads();

  int na = nt * 64 + nl, nb2 = na + 32;
  int nca = na < NN ? na : NN - 1, ncb = nb2 < NN ? nb2 : NN - 1;
  const float* S = shk + (size_t)b * DD * NN;
  float acc0[13], acc1[13];
#pragma unroll
  for (int i = 0; i < 13; ++i) { acc0[i] = 0.f; acc1[i] = 0.f; }

  for (int d = 0; d < DD; d += 4) {
    float sa0 = S[(size_t)(d + 0) * NN + nca];
    float sa1 = S[(size_t)(d + 1) * NN + nca];
    float sa2 = S[(size_t)(d + 2) * NN + nca];
    float sa3 = S[(size_t)(d + 3) * NN + nca];
    float sb0 = S[(size_t)(d + 0) * NN + ncb];
    float sb1 = S[(size_t)(d + 1) * NN + ncb];
    float sb2 = S[(size_t)(d + 2) * NN + ncb];
    float sb3 = S[(size_t)(d + 3) * NN + ncb];
#pragma unroll
    for (int i = 0; i < 13; ++i) {
      int p = pg + (i << 3);
      if (p < PP) {
        const float4 a4 = *(const float4*)&A[p * 132 + d];
        acc0[i] += a4.x * sa0 + a4.y * sa1 + a4.z * sa2 + a4.w * sa3;
        acc1[i] += a4.x * sb0 + a4.y * sb1 + a4.z * sb2 + a4.w * sb3;
      }
    }
  }
#pragma unroll
  for (int i = 0; i < 13; ++i) {
    int p = pg + (i << 3);
    if (p < PP) {
      size_t base = ((size_t)b * PP + p) * NN;
      if (na < NN) sc[base + na] = acc0[i];
      if (nb2 < NN) sc[base + nb2] = acc1[i];
    }
  }
}

// ---------------- Kernel E: fast-tanh clip + edge bias + mask + row softmax ---
__global__ __launch_bounds__(256) void k_finsm(const float* __restrict__ sc,
                                               const float* __restrict__ eb,
                                               const int* __restrict__ cn,
                                               const float* __restrict__ mask,
                                               float* __restrict__ out) {
  int bid = blockIdx.x;
  int bp = (bid & 7) * 800 + (bid >> 3);       // XCD swizzle (6400 % 8 == 0)
  int b = bp / PP;
  int t = threadIdx.x;
  int node = cn[bp];
  const float* scp = sc + (size_t)bp * NN;
  const float* ebp = eb + ((size_t)b * NN + node) * NN;
  const float* mp = mask + (size_t)bp * NN;
  const float inv_sqrtD = 0.08838834764831845f;  // 1/sqrt(128)

  float vals[4];
  float m = -1e30f;
#pragma unroll
  for (int i = 0; i < 4; ++i) {
    int n = t + (i << 8);
    if (n < NN) {
      float z = scp[n] * inv_sqrtD;
      float e = __expf(2.f * z);
      float th10 = 10.f - 20.f * __builtin_amdgcn_rcpf(e + 1.f);  // 10*tanh(z)
      float lg = th10 + ebp[n] + mp[n];
      vals[i] = lg;
      m = fmaxf(m, lg);
    } else {
      vals[i] = -1e30f;
    }
  }
#pragma unroll
  for (int off = 32; off; off >>= 1) m = fmaxf(m, __shfl_xor(m, off));
  __shared__ float red[4];
  int w = t >> 6, lane = t & 63;
  if (lane == 0) red[w] = m;
  __syncthreads();
  m = fmaxf(fmaxf(red[0], red[1]), fmaxf(red[2], red[3]));
  __syncthreads();

  float s = 0.f;
#pragma unroll
  for (int i = 0; i < 4; ++i) {
    int n = t + (i << 8);
    float e = (n < NN) ? __expf(vals[i] - m) : 0.f;
    vals[i] = e;
    s += e;
  }
#pragma unroll
  for (int off = 32; off; off >>= 1) s += __shfl_xor(s, off);
  if (lane == 0) red[w] = s;
  __syncthreads();
  s = red[0] + red[1] + red[2] + red[3];
  float inv = 1.f / s;
#pragma unroll
  for (int i = 0; i < 4; ++i) {
    int n = t + (i << 8);
    if (n < NN) out[(size_t)bp * NN + n] = vals[i] * inv;
  }
}

extern "C" void kernel_launch(void* const* d_in, const int* in_sizes, int n_in,
                              void* d_out, int out_size, void* d_ws, size_t ws_size,
                              hipStream_t stream) {
  const float* x    = (const float*)d_in[0];   // encoded_last_node (B,P,D)
  const float* mask = (const float*)d_in[1];   // ninf_mask (B,P,N)
  const float* qf   = (const float*)d_in[2];   // q_first (B,H,P,QD)
  const float* kk   = (const float*)d_in[3];   // k (B,H,NTOT,QD)
  const float* vv   = (const float*)d_in[4];   // v (B,H,NTOT,QD)
  const float* shk  = (const float*)d_in[5];   // single_head_key (B,D,N)
  const float* Wq   = (const float*)d_in[6];   // (128,128)
  const float* MC   = (const float*)d_in[7];   // (128,128)
  const float* eb   = (const float*)d_in[8];   // edge_bias (B,N,N)
  const int*   cn   = (const int*)d_in[9];     // current_node (B,P)

  float* out = (float*)d_out;
  float* ws = (float*)d_ws;
  float* q_ws = ws;                                   //   819,200 f
  float* part = ws + 819200;                          // 1,843,200 f (1024*100*18)
  float* mh   = ws + 819200 + 1843200;                //   819,200 f
  float* mt   = ws + 819200 + 1843200 + 819200;       // 9,797,632 f (B*NTOT*128)
  float* sc   = mt;  // score2 overlays mt (written only after last mt read)
  float* wqt  = ws + 13279232;                        //    16,384 f
  float* mct  = ws + 13295616;                        //    16,384 f

  hipLaunchKernelGGL(k_wt, dim3(128), dim3(256), 0, stream, Wq, MC, wqt, mct);
  hipLaunchKernelGGL(k_qcalc, dim3(400), dim3(256), 0, stream, x, wqt, qf, q_ws);
  hipLaunchKernelGGL(k_mask_t, dim3(19, 2, BB), dim3(256), 0, stream, mask, mt);
  hipLaunchKernelGGL(k_mha, dim3(1024), dim3(256), 0, stream, kk, vv, q_ws, mt, part);
  hipLaunchKernelGGL(k_combine, dim3(400), dim3(256), 0, stream, part, mct, mh);
  hipLaunchKernelGGL(k_score2, dim3(1024), dim3(256), 0, stream, mh, shk, sc);
  hipLaunchKernelGGL(k_finsm, dim3(6400), dim3(256), 0, stream, sc, eb, cn, mask, out);
}

// Round 8
// 236.266 us; speedup vs baseline: 1.1034x; 1.1034x over previous
//
#include <hip/hip_runtime.h>
#include <math.h>

#define BB 64
#define PP 100
#define NN 1000
#define DD 128
#define HH 8
#define QDQ 16
#define NTOT 1196
#define HALFK 598
#define CH 128
#define QROWS 16
#define LOG2E 1.44269504088896f

// ---------------- Kernel W: transpose Wq and MC (128x128 each) ----------------
__global__ __launch_bounds__(256) void k_wt(const float* __restrict__ Wq,
                                            const float* __restrict__ MC,
                                            float* __restrict__ WqT,
                                            float* __restrict__ MCT) {
  int r = blockIdx.x;            // output row (d)
  int t = threadIdx.x;
  int j = t & 127;
  if (t < 128) WqT[r * DD + j] = Wq[j * DD + r];
  else         MCT[r * DD + j] = MC[j * DD + r];
}

// ---------------- Kernel A: q = q_first + x @ Wq^T (LDS-staged W^T GEMM) ------
__global__ __launch_bounds__(256) void k_qcalc(const float* __restrict__ x,
                                               const float* __restrict__ WqT,
                                               const float* __restrict__ qf,
                                               float* __restrict__ qout) {
  __shared__ float sw[64 * DD];        // 32 KB: one d-half of W^T
  __shared__ float xs[QROWS * DD];     // 8 KB
  int tid = threadIdx.x;
  int row0 = blockIdx.x * QROWS;

  for (int i = tid; i < QROWS * DD / 4; i += 256)
    ((float4*)xs)[i] = ((const float4*)(x + (size_t)row0 * DD))[i];

  int j = tid & 127, rr = tid >> 7;
  float acc[8];
#pragma unroll
  for (int i = 0; i < 8; ++i) acc[i] = 0.f;

  for (int half = 0; half < 2; ++half) {
    __syncthreads();
    for (int i = tid; i < 64 * DD / 4; i += 256)
      ((float4*)sw)[i] = ((const float4*)(WqT + half * 64 * DD))[i];
    __syncthreads();
#pragma unroll
    for (int ri = 0; ri < 8; ++ri) {
      int r = 2 * ri + rr;
      float a = acc[ri];
#pragma unroll 16
      for (int d = 0; d < 64; ++d)
        a += xs[r * DD + half * 64 + d] * sw[d * DD + j];
      acc[ri] = a;
    }
  }
#pragma unroll
  for (int ri = 0; ri < 8; ++ri) {
    int bp = row0 + 2 * ri + rr;
    int b = bp / PP, p = bp % PP;
    int h = j >> 4, qd = j & 15;
    size_t qi = ((size_t)(b * HH + h) * PP + p) * QDQ + qd;
    qout[qi] = acc[ri] + qf[qi];
  }
}

// ------- Kernel F: mask transpose+pad -> mt = mask*log2e - 20 (B,NTOT,128) ----
__global__ __launch_bounds__(256) void k_mask_t(const float* __restrict__ mask,
                                                float* __restrict__ mt) {
  __shared__ float tile[64][65];
  int nt = blockIdx.x;           // 19 tiles over n (0..1215, pad to NTOT)
  int pt = blockIdx.y;           // 2 tiles over p (0..127)
  int b  = blockIdx.z;
  int tx = threadIdx.x & 63, ty = threadIdx.x >> 6;
  int n0 = nt * 64, p0 = pt * 64;
#pragma unroll
  for (int r = ty; r < 64; r += 4) {
    int p = p0 + r, n = n0 + tx;
    tile[r][tx] = (p < PP && n < NN) ? mask[((size_t)b * PP + p) * NN + n] * LOG2E - 20.f
                                     : -20.f;
  }
  __syncthreads();
#pragma unroll
  for (int r = ty; r < 64; r += 4) {
    int n = n0 + r, p = p0 + tx;
    if (n < NTOT) mt[((size_t)b * NTOT + n) * 128 + p] = tile[tx][r];
  }
}

// ---------------- Kernel B: MHA partial — 2 queries/lane, fixed-offset exp2 ---
// grid = 1024 (XCD-swizzled: 512 bh * 2 halves); block = 512 (8 waves)
// wave w handles keys {w, w+8, ...} of each 128-key chunk; each lane owns query
// slots lane and lane+64. No max tracking: scores carry a -20 offset (in mt),
// so w = exp2(s) directly; partial record = (acc[16], l), merges are sums.
__global__ __launch_bounds__(512) void k_mha(const float* __restrict__ kk,
                                             const float* __restrict__ vv,
                                             const float* __restrict__ qws,
                                             const float* __restrict__ mt,
                                             float* __restrict__ part) {
  int bid = blockIdx.x;
  int swz = (bid & 7) * 128 + (bid >> 3);      // 16 blocks of same b per XCD
  int bh = swz >> 1, half = swz & 1;
  int b = bh >> 3;
  int tid = threadIdx.x;
  int w = tid >> 6;           // wave 0..7
  int lane = tid & 63;
  int p2 = lane + 64;
  int pc2 = p2 < PP ? p2 : PP - 1;             // clamped 2nd query row

  __shared__ __align__(16) float smem_f[8192]; // 32 KB: k/v dbuf, then merge area
  float4* s4 = (float4*)smem_f;                // [buf][k 512 f4 | v 512 f4]

  float q1[QDQ], q2[QDQ];
  const float sc0 = 0.25f * LOG2E;             // fold 1/sqrt(16) and log2(e)
  {
    const float* qrow1 = qws + ((size_t)bh * PP + lane) * QDQ;
    const float* qrow2 = qws + ((size_t)bh * PP + pc2) * QDQ;
#pragma unroll
    for (int jj = 0; jj < QDQ; jj += 4) {
      float4 a4 = *(const float4*)(qrow1 + jj);
      q1[jj] = a4.x * sc0; q1[jj + 1] = a4.y * sc0;
      q1[jj + 2] = a4.z * sc0; q1[jj + 3] = a4.w * sc0;
      float4 b4 = *(const float4*)(qrow2 + jj);
      q2[jj] = b4.x * sc0; q2[jj + 1] = b4.y * sc0;
      q2[jj + 2] = b4.z * sc0; q2[jj + 3] = b4.w * sc0;
    }
  }

  float acc1[QDQ], acc2[QDQ];
#pragma unroll
  for (int jj = 0; jj < QDQ; ++jj) { acc1[jj] = 0.f; acc2[jj] = 0.f; }
  float l1 = 0.f, l2 = 0.f;

  const float4* kg4 = (const float4*)(kk + (size_t)bh * NTOT * QDQ);
  const float4* vg4 = (const float4*)(vv + (size_t)bh * NTOT * QDQ);
  int key0 = half * HALFK;
  int gbase = key0 * 4;                        // float4 index of half start
  int lim = NTOT * 4 - 1;

  float4 rk, rv;
  { int gi = gbase + tid; gi = gi < lim ? gi : lim; rk = kg4[gi]; rv = vg4[gi]; }

  int cur = 0;
  for (int c = 0; c < 5; ++c) {                // 598 = 4*128 + 86
    int base = c * CH;
    int L = HALFK - base; if (L > CH) L = CH;
    __syncthreads();                           // buf[cur] free
    s4[cur * 1024 + tid] = rk;
    s4[cur * 1024 + 512 + tid] = rv;
    __syncthreads();
    if (c < 4) {                               // prefetch next chunk into regs
      int gi = gbase + (c + 1) * 512 + tid; gi = gi < lim ? gi : lim;
      rk = kg4[gi]; rv = vg4[gi];
    }
    const float* mrow = mt + ((size_t)b * NTOT + key0 + base) * 128;
    int kb = cur * 1024, vb = cur * 1024 + 512;

    // software-pipelined mask loads (1 key ahead)
    int i0 = w;
    float nmk1 = mrow[i0 * 128 + lane];
    float nmk2 = mrow[i0 * 128 + 64 + lane];
    for (int i = w; i < L; i += 8) {
      float mk1 = nmk1, mk2 = nmk2;
      int inx = i + 8; inx = inx < L ? inx : i;
      nmk1 = mrow[inx * 128 + lane];
      nmk2 = mrow[inx * 128 + 64 + lane];

      float4 k0 = s4[kb + i * 4 + 0], k1 = s4[kb + i * 4 + 1];
      float4 k2 = s4[kb + i * 4 + 2], k3 = s4[kb + i * 4 + 3];
      float s1 = q1[0] * k0.x + q1[1] * k0.y + q1[2] * k0.z + q1[3] * k0.w
               + q1[4] * k1.x + q1[5] * k1.y + q1[6] * k1.z + q1[7] * k1.w
               + q1[8] * k2.x + q1[9] * k2.y + q1[10] * k2.z + q1[11] * k2.w
               + q1[12] * k3.x + q1[13] * k3.y + q1[14] * k3.z + q1[15] * k3.w;
      float s2 = q2[0] * k0.x + q2[1] * k0.y + q2[2] * k0.z + q2[3] * k0.w
               + q2[4] * k1.x + q2[5] * k1.y + q2[6] * k1.z + q2[7] * k1.w
               + q2[8] * k2.x + q2[9] * k2.y + q2[10] * k2.z + q2[11] * k2.w
               + q2[12] * k3.x + q2[13] * k3.y + q2[14] * k3.z + q2[15] * k3.w;
      float w1 = exp2f(s1 + mk1);              // offset -20 baked into mt
      float w2 = exp2f(s2 + mk2);
      l1 += w1; l2 += w2;
      float4 v0 = s4[vb + i * 4 + 0], v1 = s4[vb + i * 4 + 1];
      float4 v2 = s4[vb + i * 4 + 2], v3 = s4[vb + i * 4 + 3];
      acc1[0] += w1 * v0.x;  acc1[1] += w1 * v0.y;  acc1[2] += w1 * v0.z;  acc1[3] += w1 * v0.w;
      acc1[4] += w1 * v1.x;  acc1[5] += w1 * v1.y;  acc1[6] += w1 * v1.z;  acc1[7] += w1 * v1.w;
      acc1[8] += w1 * v2.x;  acc1[9] += w1 * v2.y;  acc1[10] += w1 * v2.z; acc1[11] += w1 * v2.w;
      acc1[12] += w1 * v3.x; acc1[13] += w1 * v3.y; acc1[14] += w1 * v3.z; acc1[15] += w1 * v3.w;
      acc2[0] += w2 * v0.x;  acc2[1] += w2 * v0.y;  acc2[2] += w2 * v0.z;  acc2[3] += w2 * v0.w;
      acc2[4] += w2 * v1.x;  acc2[5] += w2 * v1.y;  acc2[6] += w2 * v1.z;  acc2[7] += w2 * v1.w;
      acc2[8] += w2 * v2.x;  acc2[9] += w2 * v2.y;  acc2[10] += w2 * v2.z; acc2[11] += w2 * v2.w;
      acc2[12] += w2 * v3.x; acc2[13] += w2 * v3.y; acc2[14] += w2 * v3.z; acc2[15] += w2 * v3.w;
    }
    cur ^= 1;
  }

  // ---- 8->1 merge (pure sums), 2-phase over 4-record LDS area [4][PP][17] ----
  __syncthreads();                             // k/v data dead; reuse smem
  if (w < 4) {
    float* r = smem_f + ((size_t)w * PP + lane) * 17;
#pragma unroll
    for (int jj = 0; jj < QDQ; ++jj) r[jj] = acc1[jj];
    r[16] = l1;
    if (p2 < PP) {
      float* r2 = smem_f + ((size_t)w * PP + p2) * 17;
#pragma unroll
      for (int jj = 0; jj < QDQ; ++jj) r2[jj] = acc2[jj];
      r2[16] = l2;
    }
  }
  __syncthreads();
  if (w >= 4) {
    float* r = smem_f + ((size_t)(w - 4) * PP + lane) * 17;
#pragma unroll
    for (int jj = 0; jj < QDQ; ++jj) r[jj] += acc1[jj];
    r[16] += l1;
    if (p2 < PP) {
      float* r2 = smem_f + ((size_t)(w - 4) * PP + p2) * 17;
#pragma unroll
      for (int jj = 0; jj < QDQ; ++jj) r2[jj] += acc2[jj];
      r2[16] += l2;
    }
  }
  __syncthreads();
  for (int idx = tid; idx < PP * 17; idx += 512) {
    int pp2 = idx / 17, e = idx % 17;
    float vsum = smem_f[(0 * PP + pp2) * 17 + e] + smem_f[(1 * PP + pp2) * 17 + e]
               + smem_f[(2 * PP + pp2) * 17 + e] + smem_f[(3 * PP + pp2) * 17 + e];
    part[((size_t)swz * PP + pp2) * 17 + e] = vsum;
  }
}

// ---------------- Kernel C: merge 2 halves (sum) + mh_combine (LDS GEMM) ------
__global__ __launch_bounds__(256) void k_combine(const float* __restrict__ part,
                                                 const float* __restrict__ MCT,
                                                 float* __restrict__ mh) {
  __shared__ float sw[64 * DD];        // 32 KB
  __shared__ float oc[QROWS * DD];     // 8 KB
  int tid = threadIdx.x;
  int row0 = blockIdx.x * QROWS;

  for (int i = tid; i < QROWS * DD; i += 256) {
    int r = i >> 7, t = i & 127;
    int bp = row0 + r, b = bp / PP, p = bp % PP;
    int qd = t & 15, h = t >> 4;
    int bh = b * HH + h;
    const float* r0 = part + (((size_t)(bh * 2 + 0)) * PP + p) * 17;
    const float* r1 = part + (((size_t)(bh * 2 + 1)) * PP + p) * 17;
    float A = r0[qd] + r1[qd];
    float L = r0[16] + r1[16];
    oc[i] = A / L;
  }

  int j = tid & 127, rr = tid >> 7;
  float acc[8];
#pragma unroll
  for (int i = 0; i < 8; ++i) acc[i] = 0.f;

  for (int half = 0; half < 2; ++half) {
    __syncthreads();
    for (int i = tid; i < 64 * DD / 4; i += 256)
      ((float4*)sw)[i] = ((const float4*)(MCT + half * 64 * DD))[i];
    __syncthreads();
#pragma unroll
    for (int ri = 0; ri < 8; ++ri) {
      int r = 2 * ri + rr;
      float a = acc[ri];
#pragma unroll 16
      for (int d = 0; d < 64; ++d)
        a += oc[r * DD + half * 64 + d] * sw[d * DD + j];
      acc[ri] = a;
    }
  }
#pragma unroll
  for (int ri = 0; ri < 8; ++ri) {
    int bp = row0 + 2 * ri + rr;
    mh[(size_t)bp * DD + j] = acc[ri];
  }
}

// ---------------- Kernel D: score2[b,p,n] = sum_d mh[b,p,d]*shk[b,d,n] --------
__global__ __launch_bounds__(256) void k_score2(const float* __restrict__ mh,
                                                const float* __restrict__ shk,
                                                float* __restrict__ sc) {
  int bid = blockIdx.x;
  int swz = (bid & 7) * 128 + (bid >> 3);      // same-b blocks share an XCD
  int b = swz >> 4, nt = swz & 15;
  int tid = threadIdx.x; int nl = tid & 31, pg = tid >> 5;
  __shared__ float A[PP * 132];
  for (int idx = tid; idx < PP * DD; idx += 256)
    A[(idx >> 7) * 132 + (idx & 127)] = mh[(size_t)b * PP * DD + idx];
  __syncthreads();

  int na = nt * 64 + nl, nb2 = na + 32;
  int nca = na < NN ? na : NN - 1, ncb = nb2 < NN ? nb2 : NN - 1;
  const float* S = shk + (size_t)b * DD * NN;
  float acc0[13], acc1[13];
#pragma unroll
  for (int i = 0; i < 13; ++i) { acc0[i] = 0.f; acc1[i] = 0.f; }

  for (int d = 0; d < DD; d += 4) {
    float sa0 = S[(size_t)(d + 0) * NN + nca];
    float sa1 = S[(size_t)(d + 1) * NN + nca];
    float sa2 = S[(size_t)(d + 2) * NN + nca];
    float sa3 = S[(size_t)(d + 3) * NN + nca];
    float sb0 = S[(size_t)(d + 0) * NN + ncb];
    float sb1 = S[(size_t)(d + 1) * NN + ncb];
    float sb2 = S[(size_t)(d + 2) * NN + ncb];
    float sb3 = S[(size_t)(d + 3) * NN + ncb];
#pragma unroll
    for (int i = 0; i < 13; ++i) {
      int p = pg + (i << 3);
      if (p < PP) {
        const float4 a4 = *(const float4*)&A[p * 132 + d];
        acc0[i] += a4.x * sa0 + a4.y * sa1 + a4.z * sa2 + a4.w * sa3;
        acc1[i] += a4.x * sb0 + a4.y * sb1 + a4.z * sb2 + a4.w * sb3;
      }
    }
  }
#pragma unroll
  for (int i = 0; i < 13; ++i) {
    int p = pg + (i << 3);
    if (p < PP) {
      size_t base = ((size_t)b * PP + p) * NN;
      if (na < NN) sc[base + na] = acc0[i];
      if (nb2 < NN) sc[base + nb2] = acc1[i];
    }
  }
}

// ---------------- Kernel E: fast-tanh clip + edge bias + mask + row softmax ---
__global__ __launch_bounds__(256) void k_finsm(const float* __restrict__ sc,
                                               const float* __restrict__ eb,
                                               const int* __restrict__ cn,
                                               const float* __restrict__ mask,
                                               float* __restrict__ out) {
  int bid = blockIdx.x;
  int bp = (bid & 7) * 800 + (bid >> 3);       // XCD swizzle (6400 % 8 == 0)
  int b = bp / PP;
  int t = threadIdx.x;
  int node = cn[bp];
  const float* scp = sc + (size_t)bp * NN;
  const float* ebp = eb + ((size_t)b * NN + node) * NN;
  const float* mp = mask + (size_t)bp * NN;
  const float inv_sqrtD = 0.08838834764831845f;  // 1/sqrt(128)

  float vals[4];
  float m = -1e30f;
#pragma unroll
  for (int i = 0; i < 4; ++i) {
    int n = t + (i << 8);
    if (n < NN) {
      float z = scp[n] * inv_sqrtD;
      float e = __expf(2.f * z);
      float th10 = 10.f - 20.f * __builtin_amdgcn_rcpf(e + 1.f);  // 10*tanh(z)
      float lg = th10 + ebp[n] + mp[n];
      vals[i] = lg;
      m = fmaxf(m, lg);
    } else {
      vals[i] = -1e30f;
    }
  }
#pragma unroll
  for (int off = 32; off; off >>= 1) m = fmaxf(m, __shfl_xor(m, off));
  __shared__ float red[4];
  int w = t >> 6, lane = t & 63;
  if (lane == 0) red[w] = m;
  __syncthreads();
  m = fmaxf(fmaxf(red[0], red[1]), fmaxf(red[2], red[3]));
  __syncthreads();

  float s = 0.f;
#pragma unroll
  for (int i = 0; i < 4; ++i) {
    int n = t + (i << 8);
    float e = (n < NN) ? __expf(vals[i] - m) : 0.f;
    vals[i] = e;
    s += e;
  }
#pragma unroll
  for (int off = 32; off; off >>= 1) s += __shfl_xor(s, off);
  if (lane == 0) red[w] = s;
  __syncthreads();
  s = red[0] + red[1] + red[2] + red[3];
  float inv = 1.f / s;
#pragma unroll
  for (int i = 0; i < 4; ++i) {
    int n = t + (i << 8);
    if (n < NN) out[(size_t)bp * NN + n] = vals[i] * inv;
  }
}

extern "C" void kernel_launch(void* const* d_in, const int* in_sizes, int n_in,
                              void* d_out, int out_size, void* d_ws, size_t ws_size,
                              hipStream_t stream) {
  const float* x    = (const float*)d_in[0];   // encoded_last_node (B,P,D)
  const float* mask = (const float*)d_in[1];   // ninf_mask (B,P,N)
  const float* qf   = (const float*)d_in[2];   // q_first (B,H,P,QD)
  const float* kk   = (const float*)d_in[3];   // k (B,H,NTOT,QD)
  const float* vv   = (const float*)d_in[4];   // v (B,H,NTOT,QD)
  const float* shk  = (const float*)d_in[5];   // single_head_key (B,D,N)
  const float* Wq   = (const float*)d_in[6];   // (128,128)
  const float* MC   = (const float*)d_in[7];   // (128,128)
  const float* eb   = (const float*)d_in[8];   // edge_bias (B,N,N)
  const int*   cn   = (const int*)d_in[9];     // current_node (B,P)

  float* out = (float*)d_out;
  float* ws = (float*)d_ws;
  float* q_ws = ws;                                   //   819,200 f
  float* part = ws + 819200;                          // 1,740,800 f (1024*100*17)
  float* mh   = ws + 2560000;                         //   819,200 f
  float* mt   = ws + 3379200;                         // 9,797,632 f (B*NTOT*128)
  float* sc   = mt;  // score2 overlays mt (written only after last mt read)
  float* wqt  = ws + 13176832;                        //    16,384 f
  float* mct  = ws + 13193216;                        //    16,384 f

  hipLaunchKernelGGL(k_wt, dim3(128), dim3(256), 0, stream, Wq, MC, wqt, mct);
  hipLaunchKernelGGL(k_qcalc, dim3(400), dim3(256), 0, stream, x, wqt, qf, q_ws);
  hipLaunchKernelGGL(k_mask_t, dim3(19, 2, BB), dim3(256), 0, stream, mask, mt);
  hipLaunchKernelGGL(k_mha, dim3(1024), dim3(512), 0, stream, kk, vv, q_ws, mt, part);
  hipLaunchKernelGGL(k_combine, dim3(400), dim3(256), 0, stream, part, mct, mh);
  hipLaunchKernelGGL(k_score2, dim3(1024), dim3(256), 0, stream, mh, shk, sc);
  hipLaunchKernelGGL(k_finsm, dim3(6400), dim3(256), 0, stream, sc, eb, cn, mask, out);
}